// Round 7
// baseline (128.050 us; speedup 1.0000x reference)
//
#include <hip/hip_runtime.h>

#define B 256
#define KDIM 8
#define IDIM 1152
#define CDIM 10
#define ODIM 16
#define CO 160
#define IK 9216        // IDIM*KDIM
#define NPART 8        // split-K partials in k_s

typedef __bf16 bf16x8 __attribute__((ext_vector_type(8)));
typedef unsigned short ushort8 __attribute__((ext_vector_type(8)));
typedef float f32x4 __attribute__((ext_vector_type(4)));

__device__ __forceinline__ unsigned short f2bf(float f) {
  unsigned u = __float_as_uint(f);
  unsigned r = u + 0x7fff + ((u >> 16) & 1);   // RNE
  return (unsigned short)(r >> 16);
}

union U8B8 { ushort8 u; bf16x8 h; };

// ---------------------------------------------------------------------------
// Kernel 1 (prep): role A (blocks 0..287): x -> xtbT bf16 [b][i*8+k] and
// xtkb bf16 [i*8+k][b].  role B (288..359): W -> Wq0 = bf16(W/1152)
// [c*16+o][i*8+k]; first 45 role-B blocks zero logits.
// ---------------------------------------------------------------------------
__global__ void __launch_bounds__(256) k_prep(const float* __restrict__ x,
                                              const float* __restrict__ W,
                                              unsigned short* __restrict__ xtbT,
                                              unsigned short* __restrict__ xtkb,
                                              unsigned short* __restrict__ Wq,
                                              float* __restrict__ logits) {
  __shared__ __align__(16) unsigned char smem[41280];
  const int bid = blockIdx.x;
  const int t = threadIdx.x;
  if (bid < 288) {
    float* tf = (float*)smem;                 // tile[k][bb][ii] : k*1056+bb*33+ii
    const int i0 = (bid % 36) * 32;
    const int b0 = (bid / 36) * 32;
    const int tx = t & 31, ty = t >> 5;
#pragma unroll
    for (int r = 0; r < 4; ++r) {
      int b = b0 + ty + r * 8;
#pragma unroll
      for (int k = 0; k < 8; ++k)
        tf[k * 1056 + (ty + r * 8) * 33 + tx] =
            x[((size_t)b * KDIM + k) * IDIM + i0 + tx];
    }
    __syncthreads();
    // xtbT[b][i*8+k]  (ushort8 per (b,i))
#pragma unroll
    for (int r = 0; r < 4; ++r) {
      int idx = r * 256 + t;
      int bb = idx >> 5, ii = idx & 31;
      ushort8 v;
#pragma unroll
      for (int k = 0; k < 8; ++k) v[k] = f2bf(tf[k * 1056 + bb * 33 + ii]);
      *reinterpret_cast<ushort8*>(&xtbT[(size_t)(b0 + bb) * IK + (i0 + ii) * 8]) = v;
    }
    // xtkb[(i*8+k)][b]  (ty = k, tx = b-lane)
#pragma unroll
    for (int ii = 0; ii < 32; ++ii)
      xtkb[((size_t)(i0 + ii) * 8 + ty) * B + b0 + tx] =
          f2bf(tf[ty * 1056 + tx * 33 + ii]);
  } else {
    unsigned short* wt = (unsigned short*)smem;  // wt[ii][j], row stride 1288
    const int bz = bid - 288;                    // 0..71
    const int i0 = bz * 16;
    const float sc = 1.f / (float)IDIM;
#pragma unroll
    for (int ii = 0; ii < 16; ++ii) {
      const float* src = &W[(size_t)(i0 + ii) * 1280];
#pragma unroll
      for (int p = 0; p < 5; ++p) {
        int j = p * 256 + t;
        wt[ii * 1288 + j] = f2bf(src[j] * sc);
      }
    }
    __syncthreads();
#pragma unroll
    for (int p = 0; p < 10; ++p) {
      int idx = p * 256 + t;
      int co = idx >> 4, ii = idx & 15;
      ushort8 v = *reinterpret_cast<const ushort8*>(&wt[ii * 1288 + co * 8]);
      *reinterpret_cast<ushort8*>(&Wq[(size_t)co * IK + (i0 + ii) * 8]) = v;
    }
    if (bz < 45) logits[bz * 256 + t] = 0.f;
  }
}

// ---------------------------------------------------------------------------
// Kernel 2 (k_q): per-class softmax over i, then Wq[c*16+o][ik] = bf16(W*q).
// grid (10 c, 4 o-quads), block 256. Softmax redundant x4 per class (tiny).
// ---------------------------------------------------------------------------
__global__ void __launch_bounds__(256) k_q(const float* __restrict__ logits,
                                           const float* __restrict__ W,
                                           unsigned short* __restrict__ Wq) {
  const int c = blockIdx.x;
  const int o0 = blockIdx.y * 4;
  const int t = threadIdx.x;
  __shared__ float cls[IDIM];
  __shared__ float red4[4];

  float m = -1e30f;
  for (int i = t; i < IDIM; i += 256) {
    float v = logits[i * CDIM + c];
    cls[i] = v;
    m = fmaxf(m, v);
  }
#pragma unroll
  for (int off = 32; off; off >>= 1) m = fmaxf(m, __shfl_xor(m, off));
  if ((t & 63) == 0) red4[t >> 6] = m;
  __syncthreads();
  m = fmaxf(fmaxf(red4[0], red4[1]), fmaxf(red4[2], red4[3]));
  __syncthreads();
  float ps = 0.f;
  for (int i = t; i < IDIM; i += 256) {
    float e = expf(cls[i] - m);
    cls[i] = e;
    ps += e;
  }
#pragma unroll
  for (int off = 32; off; off >>= 1) ps += __shfl_xor(ps, off);
  if ((t & 63) == 0) red4[t >> 6] = ps;
  __syncthreads();
  const float rinv = 1.f / (red4[0] + red4[1] + red4[2] + red4[3]);

#pragma unroll
  for (int r = 0; r < 4; ++r) {
    int row = c * 16 + o0 + r;
    for (int i = t; i < IDIM; i += 256) {
      const float* src = &W[((size_t)i * CDIM + c) * 128 + (o0 + r) * 8];
      float q = cls[i] * rinv;
      float4 w0 = *(const float4*)src;
      float4 w1 = *(const float4*)(src + 4);
      ushort8 v;
      v[0] = f2bf(w0.x * q); v[1] = f2bf(w0.y * q);
      v[2] = f2bf(w0.z * q); v[3] = f2bf(w0.w * q);
      v[4] = f2bf(w1.x * q); v[5] = f2bf(w1.y * q);
      v[6] = f2bf(w1.z * q); v[7] = f2bf(w1.w * q);
      *reinterpret_cast<ushort8*>(&Wq[(size_t)row * IK + i * 8]) = v;
    }
  }
}

// ---------------------------------------------------------------------------
// Kernel 3 (k_s): s[o,b] = sum_ik Wq[c*16+o][ik] * xtbT[b][ik].
// grid (16 bt, 10 c, 8 g), ONE wave per block. Each g-split covers
// IK/NPART = 1152 K-elements = 36 chunks of 32 (FIX: was 9 -> 1/4 coverage).
// ---------------------------------------------------------------------------
__global__ void __launch_bounds__(64) k_s(const unsigned short* __restrict__ Wq,
                                          const unsigned short* __restrict__ xtbT,
                                          float* __restrict__ s_part) {
  const int bt = blockIdx.x, c = blockIdx.y, g = blockIdx.z;
  const int l = threadIdx.x;
  const int lr = l & 15, lq = l >> 4;
  const unsigned short* Ap = &Wq[(size_t)(c * 16 + lr) * IK + lq * 8];
  const unsigned short* Bp = &xtbT[(size_t)(bt * 16 + lr) * IK + lq * 8];
  f32x4 acc = (f32x4){0.f, 0.f, 0.f, 0.f};
#pragma unroll 6
  for (int t9 = 0; t9 < 36; ++t9) {
    const int off = (g * 36 + t9) * 32;
    U8B8 a; a.u = *reinterpret_cast<const ushort8*>(Ap + off);
    U8B8 b; b.u = *reinterpret_cast<const ushort8*>(Bp + off);
    acc = __builtin_amdgcn_mfma_f32_16x16x32_bf16(a.h, b.h, acc, 0, 0, 0);
  }
  // D: col = b = lr, rows o = lq*4+j (consecutive co) -> one float4
  *reinterpret_cast<f32x4*>(
      &s_part[((size_t)g * B + bt * 16 + lr) * CO + c * 16 + lq * 4]) = acc;
}

// ---------------------------------------------------------------------------
// Kernel 4a (k_sqm, iters 0/1): reduce split-K partials + squash ->
// outT bf16 [co][b] (the B-operand layout for MFMA k_agr).
// grid 16, block 256: lane = b (coalesced), t>>4 = o.
// ---------------------------------------------------------------------------
__global__ void __launch_bounds__(256) k_sqm(const float* __restrict__ s_part,
                                             unsigned short* __restrict__ outT) {
  const int t = threadIdx.x;
  const int b = blockIdx.x * 16 + (t & 15);
  const int o = t >> 4;
  float v[CDIM];
  float ns = 0.f;
#pragma unroll
  for (int c = 0; c < CDIM; ++c) {
    float sv = 0.f;
#pragma unroll
    for (int p = 0; p < NPART; ++p)
      sv += s_part[((size_t)p * B + b) * CO + c * 16 + o];
    v[c] = sv;
    ns += sv * sv;
  }
  float f = (ns / (1.f + ns)) / (sqrtf(ns) + 1e-10f);
#pragma unroll
  for (int c = 0; c < CDIM; ++c)
    outT[(c * 16 + o) * B + b] = f2bf(v[c] * f);
}

// ---------------------------------------------------------------------------
// Kernel 4b (k_sqf, last iter): reduce + squash -> d_out f32 [b][c][o].
// ---------------------------------------------------------------------------
__global__ void __launch_bounds__(256) k_sqf(const float* __restrict__ s_part,
                                             float* __restrict__ out) {
  int idx = blockIdx.x * 256 + threadIdx.x;
  int b = idx >> 4, o = idx & 15;
  float v[CDIM];
#pragma unroll
  for (int c = 0; c < CDIM; ++c) v[c] = 0.f;
#pragma unroll
  for (int p = 0; p < NPART; ++p) {
    const float* row = &s_part[((size_t)p * B + b) * CO + o];
#pragma unroll
    for (int c = 0; c < CDIM; ++c) v[c] += row[c * 16];
  }
  float ns = 0.f;
#pragma unroll
  for (int c = 0; c < CDIM; ++c) ns += v[c] * v[c];
  float f = (ns / (1.f + ns)) / (sqrtf(ns) + 1e-10f);
#pragma unroll
  for (int c = 0; c < CDIM; ++c) out[(size_t)b * CO + c * 16 + o] = v[c] * f;
}

// ---------------------------------------------------------------------------
// Kernel 5 (k_agr, MFMA): y[ik][co] = sum_b xtkb[ik][b] * outT[co][b]
// (partial over this block's 64 b's), then agr[i,c] = (1/B) sum_ok W*y,
// atomicAdd into logits.  grid (144 i-tiles of 8, 4 b-splits), block 256.
// Wave w owns m-tile w (16 ik rows) x all 10 n-tiles x 2 K-chunks.
// ---------------------------------------------------------------------------
__global__ void __launch_bounds__(256) k_agr(const float* __restrict__ W,
                                             const unsigned short* __restrict__ xtkb,
                                             const unsigned short* __restrict__ outT,
                                             float* __restrict__ logits) {
  const int bx = blockIdx.x;
  const int bh = blockIdx.y;
  const int t = threadIdx.x, w = t >> 6, l = t & 63;
  const int lr = l & 15, lq = l >> 4;
  __shared__ float yl[64][161];

  f32x4 acc[10];
#pragma unroll
  for (int nt = 0; nt < 10; ++nt) acc[nt] = (f32x4){0.f, 0.f, 0.f, 0.f};

  const unsigned short* Ap = &xtkb[(size_t)(bx * 64 + w * 16 + lr) * B + bh * 64 + lq * 8];
  const unsigned short* Bp = &outT[(size_t)lr * B + bh * 64 + lq * 8];

#pragma unroll
  for (int kc = 0; kc < 2; ++kc) {
    U8B8 a; a.u = *reinterpret_cast<const ushort8*>(Ap + kc * 32);
#pragma unroll
    for (int nt = 0; nt < 10; ++nt) {
      U8B8 bv; bv.u = *reinterpret_cast<const ushort8*>(Bp + (size_t)nt * 16 * B + kc * 32);
      acc[nt] = __builtin_amdgcn_mfma_f32_16x16x32_bf16(a.h, bv.h, acc[nt], 0, 0, 0);
    }
  }
  // D: rows m = ik = w*16 + lq*4 + j, cols n = co = nt*16 + lr
#pragma unroll
  for (int nt = 0; nt < 10; ++nt)
#pragma unroll
    for (int j = 0; j < 4; ++j)
      yl[w * 16 + lq * 4 + j][nt * 16 + lr] = acc[nt][j];
  __syncthreads();

  if (t < 160) {
    const int ii = t / 20, rem = t % 20, cc = rem >> 1, oh = rem & 1;
    const float* Wp = &W[((size_t)(bx * 8 + ii) * CDIM + cc) * 128 + oh * 64];
    float sum = 0.f;
#pragma unroll
    for (int o = 0; o < 8; ++o) {
      float4 w0 = *(const float4*)(&Wp[o * 8]);
      float4 w1 = *(const float4*)(&Wp[o * 8 + 4]);
      int co = cc * 16 + oh * 8 + o;
      sum += w0.x * yl[ii * 8 + 0][co] + w0.y * yl[ii * 8 + 1][co]
           + w0.z * yl[ii * 8 + 2][co] + w0.w * yl[ii * 8 + 3][co]
           + w1.x * yl[ii * 8 + 4][co] + w1.y * yl[ii * 8 + 5][co]
           + w1.z * yl[ii * 8 + 6][co] + w1.w * yl[ii * 8 + 7][co];
    }
    sum += __shfl_xor(sum, 1);
    if (oh == 0) atomicAdd(&logits[(bx * 8 + ii) * CDIM + cc], sum * (1.f / (float)B));
  }
}

// ---------------------------------------------------------------------------
extern "C" void kernel_launch(void* const* d_in, const int* in_sizes, int n_in,
                              void* d_out, int out_size, void* d_ws, size_t ws_size,
                              hipStream_t stream) {
  const float* x = (const float*)d_in[0];       // [B,K,I] f32
  const float* W = (const float*)d_in[1];       // [I,C,O,K] f32
  float* out = (float*)d_out;                   // [B,C,O,1] f32

  float* logits = (float*)d_ws;                              // I*C f32
  float* s_part = logits + IDIM * CDIM;                      // NPART*B*CO f32
  unsigned short* xtbT = (unsigned short*)(s_part + (size_t)NPART * B * CO); // B*IK
  unsigned short* xtkb = xtbT + (size_t)B * IK;              // IK*B
  unsigned short* Wq   = xtkb + (size_t)IK * B;              // CO*IK
  unsigned short* outT = Wq + (size_t)CO * IK;               // CO*B

  k_prep<<<360, 256, 0, stream>>>(x, W, xtbT, xtkb, Wq, logits);

  for (int it = 0; it < 3; ++it) {
    k_s<<<dim3(16, CDIM, NPART), 64, 0, stream>>>(Wq, xtbT, s_part);
    if (it < 2) {
      k_sqm<<<16, 256, 0, stream>>>(s_part, outT);
      k_agr<<<dim3(144, 4), 256, 0, stream>>>(W, xtkb, outT, logits);
      k_q<<<dim3(CDIM, 4), 256, 0, stream>>>(logits, W, Wq);
    } else {
      k_sqf<<<16, 256, 0, stream>>>(s_part, out);
    }
  }
}